// Round 2
// baseline (8299.520 us; speedup 1.0000x reference)
//
#include <hip/hip_runtime.h>
#include <hip/hip_bf16.h>

#define NLAY 8
#define NH 4
#define DIM 64
#define VDIM 128
#define QHD 16
#define VHD 32
#define TT 17
#define FFND 12

template <bool BF16>
__device__ __forceinline__ float ld(const void* p, int i) {
  if (BF16) return __bfloat162float(((const __hip_bfloat16*)p)[i]);
  return ((const float*)p)[i];
}

// Build sin/cos/dmask tables in ws (fp32) + detect input dtype.
// ws[0..271]=sin (17x16), ws[272..543]=cos, ws[544..1699]=dmask (4x17x17),
// ws[1700]=dtype flag (1.0 = bf16 storage, 0.0 = fp32 storage)
__global__ void setup_tables(float* __restrict__ ws, const void* __restrict__ x) {
  int tid = threadIdx.x;
  for (int idx = tid; idx < 272; idx += 256) {
    int t = idx >> 4, j = idx & 15;
    float a = powf(10000.f, -(float)(j >> 1) / 7.f);
    float arg = (float)t * a;
    ws[idx] = sinf(arg);
    ws[272 + idx] = cosf(arg);
  }
  for (int row = tid; row < 68; row += 256) {
    int hh = row / 17, t = row % 17;
    float gamma = 1.f - exp2f(-5.f - 4.f * (float)hh / 3.f);
    float sum = 0.f;
    for (int u = 0; u <= t; ++u) sum += powf(gamma, (float)(t - u));
    float rn = rsqrtf(sum);
    for (int u = 0; u < 17; ++u)
      ws[544 + row * 17 + u] = (u <= t) ? powf(gamma, (float)(t - u)) * rn : 0.f;
  }
  if (tid == 0) {
    // bf16 is the top half of fp32. Read EVEN-index elements as bf16:
    // if storage is fp32, these are mantissa bits -> random exponent, ~16% sane;
    // if storage is bf16, these are real N(0,1) samples, ~100% sane.
    const unsigned short* u16 = (const unsigned short*)x;
    int sane = 0;
    for (int i = 0; i < 128; ++i) {
      unsigned int bits = ((unsigned int)u16[2 * i]) << 16;
      float v = __uint_as_float(bits);
      float av = fabsf(v);
      if (v == 0.f || (av > 1e-8f && av < 1e4f)) sane++;
    }
    ws[1700] = (sane >= 64) ? 1.f : 0.f;
  }
}

template <bool BF16>
__global__ void __launch_bounds__(256, 2)
vit_fused(const void* __restrict__ x,
          const void* __restrict__ patch_w,
          const void* __restrict__ patch_b,
          const void* __restrict__ cls,
          const void* __restrict__ pos,
          const void* __restrict__ Wq,
          const void* __restrict__ Wk,
          const void* __restrict__ Wv,
          const void* __restrict__ Wg,
          const void* __restrict__ Wo,
          const void* __restrict__ ln1s,
          const void* __restrict__ ln1b,
          const void* __restrict__ w1,
          const void* __restrict__ b1,
          const void* __restrict__ w2,
          const void* __restrict__ b2,
          const void* __restrict__ ln2s,
          const void* __restrict__ ln2b,
          const void* __restrict__ lnfs,
          const void* __restrict__ lnfb,
          const void* __restrict__ neckw,
          const void* __restrict__ neckb,
          const void* __restrict__ headw,
          const void* __restrict__ headb,
          const float* __restrict__ tab,
          void* __restrict__ out) {
  // dtype dispatch: only the instantiation matching detected storage runs
  if ((tab[1700] > 0.5f) != BF16) return;

  const int b = blockIdx.x;
  const int tid = threadIdx.x;

  __shared__ float sm[14196];
  float* sH   = sm + 0;      // 17*64 residual stream
  float* sXN  = sm + 1088;   // 17*64 ln output
  float* sQ   = sm + 2176;   // 17*64
  float* sK   = sm + 3264;   // 17*64
  float* sV   = sm + 4352;   // 17*128
  float* sG   = sm + 6528;   // 17*128
  float* sSC  = sm + 8704;   // 4*17*17 scores
  float* sOO  = sm + 9860;   // 17*128
  float* sSin = sm + 12036;  // 17*16
  float* sCos = sm + 12308;  // 17*16
  float* sDM  = sm + 12580;  // 4*17*17
  float* sFF  = sm + 13736;  // 17*12
  float* sST  = sm + 13940;  // 256 scratch stats
  float* sPX  = sSC;         // 3072 image pixels, aliases sSC+sOO (pre-layer only)

  // ---- stage image + tables into LDS ----
  for (int i = tid; i < 3072; i += 256) sPX[i] = ld<BF16>(x, b * 3072 + i);
  for (int i = tid; i < 272; i += 256) { sSin[i] = tab[i]; sCos[i] = tab[272 + i]; }
  for (int i = tid; i < 1156; i += 256) sDM[i] = tab[544 + i];
  __syncthreads();

  // ---- patch embed + cls + pos -> sH ----
  for (int idx = tid; idx < TT * DIM; idx += 256) {
    int t = idx >> 6, d = idx & 63;
    float v;
    if (t == 0) {
      v = ld<BF16>(cls, d);
    } else {
      int p = t - 1, pi = p >> 2, pj = p & 3;
      float acc = ld<BF16>(patch_b, d);
      for (int c = 0; c < 3; ++c)
        for (int a = 0; a < 8; ++a)
          for (int bb = 0; bb < 8; ++bb)
            acc += sPX[c * 1024 + (pi * 8 + a) * 32 + pj * 8 + bb] *
                   ld<BF16>(patch_w, (c * 64 + a * 8 + bb) * 64 + d);
      v = acc;
    }
    sH[idx] = v + ld<BF16>(pos, idx);
  }
  __syncthreads();

  const float4* xn4 = (const float4*)sXN;
  const float4* oo4 = (const float4*)sOO;

  for (int l = 0; l < NLAY; ++l) {
    const int oQ = l * DIM * DIM;
    const int oV = l * DIM * VDIM;
    const int oO = l * VDIM * DIM;

    // ---- ln1 ----
    if (tid < TT) {
      float s1 = 0.f, s2 = 0.f;
      for (int d = 0; d < DIM; ++d) { float v = sH[tid * 64 + d]; s1 += v; s2 += v * v; }
      float mu = s1 * (1.f / 64.f);
      float var = s2 * (1.f / 64.f) - mu * mu;
      sST[tid] = mu;
      sST[17 + tid] = rsqrtf(var + 1e-5f);
    }
    __syncthreads();
    for (int idx = tid; idx < TT * DIM; idx += 256) {
      int t = idx >> 6, d = idx & 63;
      sXN[idx] = (sH[idx] - sST[t]) * sST[17 + t] * ld<BF16>(ln1s, l * 64 + d) +
                 ld<BF16>(ln1b, l * 64 + d);
    }
    __syncthreads();

    // ---- q,k,v,g projections (384 output columns, dot over 64) ----
    for (int col = tid; col < 384; col += 256) {
      const void* W; float* dst; int nc, j, off;
      if (col < 64)       { W = Wq; dst = sQ; nc = 64;  j = col;       off = oQ; }
      else if (col < 128) { W = Wk; dst = sK; nc = 64;  j = col - 64;  off = oQ; }
      else if (col < 256) { W = Wv; dst = sV; nc = 128; j = col - 128; off = oV; }
      else                { W = Wg; dst = sG; nc = 128; j = col - 256; off = oV; }
      float acc[17];
#pragma unroll
      for (int t = 0; t < 17; ++t) acc[t] = 0.f;
      for (int d4 = 0; d4 < 16; ++d4) {
        float w0 = ld<BF16>(W, off + (d4 * 4 + 0) * nc + j);
        float w1_ = ld<BF16>(W, off + (d4 * 4 + 1) * nc + j);
        float w2_ = ld<BF16>(W, off + (d4 * 4 + 2) * nc + j);
        float w3 = ld<BF16>(W, off + (d4 * 4 + 3) * nc + j);
#pragma unroll
        for (int t = 0; t < 17; ++t) {
          float4 xv = xn4[t * 16 + d4];
          acc[t] += xv.x * w0 + xv.y * w1_ + xv.z * w2_ + xv.w * w3;
        }
      }
#pragma unroll
      for (int t = 0; t < 17; ++t) dst[t * nc + j] = acc[t];
    }
    __syncthreads();

    // ---- rotary on q,k (k also * QH^-0.5 = 0.25) ----
    for (int idx = tid; idx < 1088; idx += 256) {
      int which = idx >= 544;             // 0 = q, 1 = k
      int r = which ? idx - 544 : idx;
      int t = r >> 5, pr = r & 31;
      int d0 = pr * 2;
      int jj = d0 & 15;
      float sv = sSin[t * 16 + jj], cv = sCos[t * 16 + jj];
      float* buf = which ? sK : sQ;
      float x0 = buf[t * 64 + d0], x1 = buf[t * 64 + d0 + 1];
      float scale = which ? 0.25f : 1.f;
      buf[t * 64 + d0]     = (x0 * cv - x1 * sv) * scale;
      buf[t * 64 + d0 + 1] = (x1 * cv + x0 * sv) * scale;
    }
    __syncthreads();

    // ---- scores = (q . k) * dmask ----
    for (int idx = tid; idx < 1156; idx += 256) {
      int hh = idx / 289, r = idx % 289;
      int t = r / 17, u = r % 17;
      float acc = 0.f;
      if (u <= t) {
        float dm = sDM[idx];
#pragma unroll
        for (int j = 0; j < 16; ++j)
          acc += sQ[t * 64 + hh * 16 + j] * sK[u * 64 + hh * 16 + j];
        acc *= dm;
      }
      sSC[idx] = acc;
    }
    __syncthreads();
    // row denominators: 1 / clip(|row sum|, 1, inf)
    if (tid < 68) {
      int base = tid * 17;
      float s = 0.f;
      for (int u = 0; u < 17; ++u) s += sSC[base + u];
      float den = fabsf(s);
      if (den < 1.f) den = 1.f;
      sST[34 + tid] = 1.f / den;
    }
    __syncthreads();

    // ---- o = (scores/denom) @ v -> sOO[t][h*32+j] ----
    for (int idx = tid; idx < 2176; idx += 256) {
      int hh = idx / 544, r = idx % 544;
      int t = r >> 5, j = r & 31;
      float acc = 0.f;
#pragma unroll
      for (int u = 0; u < 17; ++u)
        acc += sSC[hh * 289 + t * 17 + u] * sV[u * 128 + hh * 32 + j];
      sOO[t * 128 + hh * 32 + j] = acc * sST[34 + hh * 17 + t];
    }
    __syncthreads();

    // ---- per-(h,t) group norm over 32, then silu(g) gating ----
    if (tid < 68) {
      int hh = tid / 17, t = tid % 17;
      float s1 = 0.f, s2 = 0.f;
      for (int j = 0; j < 32; ++j) { float v = sOO[t * 128 + hh * 32 + j]; s1 += v; s2 += v * v; }
      float mu = s1 * (1.f / 32.f);
      float var = s2 * (1.f / 32.f) - mu * mu;
      sST[102 + tid] = mu;
      sST[170 + tid] = rsqrtf(var + 1e-5f);
    }
    __syncthreads();
    for (int idx = tid; idx < 2176; idx += 256) {
      int t = idx >> 7, c = idx & 127;
      int hh = c >> 5;
      float on = (sOO[idx] - sST[102 + hh * 17 + t]) * sST[170 + hh * 17 + t];
      float gv = sG[idx];
      float sil = gv / (1.f + __expf(-gv));
      sOO[idx] = sil * on;
    }
    __syncthreads();

    // ---- @ Wo (128->64) + residual into sH ----
    {
      int d = tid & 63, tq = tid >> 6;
      float acc[5] = {0.f, 0.f, 0.f, 0.f, 0.f};
      for (int c4 = 0; c4 < 32; ++c4) {
        float w0 = ld<BF16>(Wo, oO + (c4 * 4 + 0) * 64 + d);
        float w1_ = ld<BF16>(Wo, oO + (c4 * 4 + 1) * 64 + d);
        float w2_ = ld<BF16>(Wo, oO + (c4 * 4 + 2) * 64 + d);
        float w3 = ld<BF16>(Wo, oO + (c4 * 4 + 3) * 64 + d);
#pragma unroll
        for (int s = 0; s < 5; ++s) {
          int t = tq + s * 4;
          if (t < 17) {
            float4 ov = oo4[t * 32 + c4];
            acc[s] += ov.x * w0 + ov.y * w1_ + ov.z * w2_ + ov.w * w3;
          }
        }
      }
#pragma unroll
      for (int s = 0; s < 5; ++s) {
        int t = tq + s * 4;
        if (t < 17) sH[t * 64 + d] += acc[s];
      }
    }
    __syncthreads();

    // ---- ln2 ----
    if (tid < TT) {
      float s1 = 0.f, s2 = 0.f;
      for (int d = 0; d < DIM; ++d) { float v = sH[tid * 64 + d]; s1 += v; s2 += v * v; }
      float mu = s1 * (1.f / 64.f);
      float var = s2 * (1.f / 64.f) - mu * mu;
      sST[tid] = mu;
      sST[17 + tid] = rsqrtf(var + 1e-5f);
    }
    __syncthreads();
    for (int idx = tid; idx < TT * DIM; idx += 256) {
      int t = idx >> 6, d = idx & 63;
      sXN[idx] = (sH[idx] - sST[t]) * sST[17 + t] * ld<BF16>(ln2s, l * 64 + d) +
                 ld<BF16>(ln2b, l * 64 + d);
    }
    __syncthreads();

    // ---- FFN up (64->12) + gelu(tanh approx) ----
    if (tid < 204) {
      int t = tid / 12, e = tid % 12;
      float acc = ld<BF16>(b1, l * 12 + e);
      for (int d = 0; d < 64; ++d)
        acc += sXN[t * 64 + d] * ld<BF16>(w1, (l * 64 + d) * 12 + e);
      float inner = 0.7978845608028654f * (acc + 0.044715f * acc * acc * acc);
      sFF[tid] = 0.5f * acc * (1.f + tanhf(inner));
    }
    __syncthreads();

    // ---- FFN down (12->64) + residual ----
    for (int idx = tid; idx < TT * DIM; idx += 256) {
      int t = idx >> 6, d = idx & 63;
      float acc = ld<BF16>(b2, l * 64 + d);
#pragma unroll
      for (int e = 0; e < 12; ++e)
        acc += sFF[t * 12 + e] * ld<BF16>(w2, (l * 12 + e) * 64 + d);
      sH[idx] += acc;
    }
    __syncthreads();
  }

  // ---- final: lnf on last token, neck, head ----
  if (tid == 0) {
    float s1 = 0.f, s2 = 0.f;
    for (int d = 0; d < 64; ++d) { float v = sH[16 * 64 + d]; s1 += v; s2 += v * v; }
    float mu = s1 * (1.f / 64.f);
    float var = s2 * (1.f / 64.f) - mu * mu;
    sST[0] = mu;
    sST[1] = rsqrtf(var + 1e-5f);
  }
  __syncthreads();
  if (tid < 16) {
    float acc = ld<BF16>(neckb, tid);
    for (int d = 0; d < 64; ++d) {
      float yn = (sH[16 * 64 + d] - sST[0]) * sST[1] * ld<BF16>(lnfs, d) + ld<BF16>(lnfb, d);
      acc += yn * ld<BF16>(neckw, d * 16 + tid);
    }
    sST[2 + tid] = acc;
  }
  __syncthreads();
  if (tid < 10) {
    float acc = ld<BF16>(headb, tid);
#pragma unroll
    for (int e = 0; e < 16; ++e) acc += sST[2 + e] * ld<BF16>(headw, e * 10 + tid);
    if (BF16) ((__hip_bfloat16*)out)[b * 10 + tid] = __float2bfloat16(acc);
    else      ((float*)out)[b * 10 + tid] = acc;
  }
}

extern "C" void kernel_launch(void* const* d_in, const int* in_sizes, int n_in,
                              void* d_out, int out_size, void* d_ws, size_t ws_size,
                              hipStream_t stream) {
  float* tab = (float*)d_ws;
  setup_tables<<<dim3(1), dim3(256), 0, stream>>>(tab, d_in[0]);

  const int B = in_sizes[0] / (3 * 32 * 32);
  const void* in[24];
  for (int i = 0; i < 24; ++i) in[i] = d_in[i];

  // Launch both dtype instantiations; the one matching the detected storage
  // (flag in tab[1700]) does the work, the other exits immediately.
  vit_fused<false><<<dim3(B), dim3(256), 0, stream>>>(
      in[0], in[1], in[2], in[3], in[4], in[5], in[6], in[7], in[8], in[9],
      in[10], in[11], in[12], in[13], in[14], in[15], in[16], in[17], in[18],
      in[19], in[20], in[21], in[22], in[23], (const float*)tab, d_out);
  vit_fused<true><<<dim3(B), dim3(256), 0, stream>>>(
      in[0], in[1], in[2], in[3], in[4], in[5], in[6], in[7], in[8], in[9],
      in[10], in[11], in[12], in[13], in[14], in[15], in[16], in[17], in[18],
      in[19], in[20], in[21], in[22], in[23], (const float*)tab, d_out);
}